// Round 1
// baseline (19344.783 us; speedup 1.0000x reference)
//
#include <hip/hip_runtime.h>

// GRU decoder: B=64, T=1000, N=512.
// Phase 1 (pack_split): h_enc fp32 -> per-(b,t) row of [hi[512] | lo[512]] bf16
//   packed INTO d_out (4 bytes/element, same footprint as the fp32 output).
// Phase 2 (gru_scan): persistent cooperative kernel, 256 WGs x 384 threads.
//   - WG = (b-group of 8 rows, 16 hidden cols). 6 waves: {X,H} x {r,z,n} tiles.
//   - Weights pre-split to bf16 hi/lo and held in VGPRs (128 VGPR/wave) for the
//     whole scan -> immune to the per-step L2 invalidate needed for h coherence.
//   - Each GEMM = 3 MFMAs/chunk (Ahi*Bhi + Ahi*Blo + Alo*Bhi) => ~fp32 accuracy.
//   - h state: bf16 hi/lo planes, double-buffered in d_ws; h fp32 master stays
//     in gating-thread registers (each WG owns its (b,c) slice forever).
//   - Sync: per-b-group monotonic counter barrier (8 domains x 32 WGs),
//     agent-scope atomics + __threadfence (wbL2/inv) for cross-XCD visibility.
//   - out[b,t-1] written during step t (after the barrier), so overwriting the
//     packed-x region is race-free; final row flushed after the loop.

#define T_STEPS 1000
#define NDIM    512
#define BATCH   64
#define BT      8      // batch rows per WG (MFMA M=16, rows 8..15 zero-padded)
#define CT      16     // hidden cols per WG -> 3 gate N-tiles of 16
#define CGRP    32     // 512 / CT col-groups
#define BGRP    8      // 64 / BT  b-groups
#define NBLK    256
#define NTHR    384    // 6 waves

using short8  = __attribute__((ext_vector_type(8))) short;
using float4v = __attribute__((ext_vector_type(4))) float;

__device__ __forceinline__ unsigned short f2bf(float f) {
    unsigned u = __float_as_uint(f);
    return (unsigned short)((u + 0x7FFFu + ((u >> 16) & 1u)) >> 16);  // RNE
}
__device__ __forceinline__ float bf2f(unsigned short h) {
    return __uint_as_float(((unsigned)h) << 16);
}

// ---------- Phase 1: split h_enc into bf16 hi/lo planes packed in d_out ----------
__global__ void pack_split(const float* __restrict__ x, unsigned short* __restrict__ out) {
    size_t i = ((size_t)blockIdx.x * blockDim.x + threadIdx.x) * 4;  // 4 elems/thread
    size_t row = i >> 9;          // b*T + t
    int    k   = (int)(i & 511);
    const float4 v = *(const float4*)(x + i);
    float vv[4] = {v.x, v.y, v.z, v.w};
    ushort4 hi, lo;
    unsigned short h0 = f2bf(vv[0]), h1 = f2bf(vv[1]), h2 = f2bf(vv[2]), h3 = f2bf(vv[3]);
    hi = {h0, h1, h2, h3};
    lo = {f2bf(vv[0] - bf2f(h0)), f2bf(vv[1] - bf2f(h1)),
          f2bf(vv[2] - bf2f(h2)), f2bf(vv[3] - bf2f(h3))};
    unsigned short* r = out + row * 1024;
    *(ushort4*)(r + k)       = hi;
    *(ushort4*)(r + 512 + k) = lo;
}

// ---------- Phase 2: persistent scan ----------
__global__ void __launch_bounds__(NTHR, 2) gru_scan(
    const unsigned short* xpk,   // packed x (aliases out! no __restrict__)
    float* out,
    const float* __restrict__ Wih, const float* __restrict__ Whh,
    const float* __restrict__ bih, const float* __restrict__ bhh,
    unsigned short* hbuf,        // ws: hi plane [2][64][512], then lo plane
    unsigned* cnt)
{
    const int tid  = threadIdx.x;
    const int wave = tid >> 6;
    const int lane = tid & 63;
    const int m    = lane & 15;   // MFMA 16-index (A: b-row, B: gate col)
    const int q    = lane >> 4;   // k-quad
    const int wg   = blockIdx.x;
    const int bg   = wg & (BGRP - 1);
    const int cg   = wg >> 3;
    const int b0   = bg * BT;
    const int c0   = cg * CT;
    const int g    = (wave >= 3) ? 1 : 0;  // 0 = X-proj, 1 = H-proj
    const int nt   = wave - 3 * g;         // gate: 0=r, 1=z, 2=n

    // ---- persistent weight fragments: W[gate*512 + c0 + n][k], bf16 hi/lo ----
    const float* W    = g ? Whh : Wih;
    const float* wrow = W + (size_t)((nt << 9) + c0 + m) * NDIM;
    short8 wh[16], wl[16];
#pragma unroll
    for (int ch = 0; ch < 16; ++ch) {
        const float* p = wrow + ch * 32 + q * 8;
        short8 h8, l8;
#pragma unroll
        for (int j = 0; j < 8; ++j) {
            float w = p[j];
            unsigned short hb = f2bf(w);
            h8[j] = (short)hb;
            l8[j] = (short)f2bf(w - bf2f(hb));
        }
        wh[ch] = h8; wl[ch] = l8;
    }

    // ---- gating-thread state (threads 0..127 own one (b,c) forever) ----
    const int gb = tid >> 4;   // 0..7
    const int gc = tid & 15;   // 0..15
    float bxr = 0, bxz = 0, bxn = 0, bhr = 0, bhz = 0, bhn = 0, hprev = 0.f;
    size_t out_base = 0;
    if (tid < 128) {
        int cglob = c0 + gc;
        bxr = bih[cglob]; bxz = bih[512 + cglob]; bxn = bih[1024 + cglob];
        bhr = bhh[cglob]; bhz = bhh[512 + cglob]; bhn = bhh[1024 + cglob];
        out_base = ((size_t)(b0 + gb) * T_STEPS) * NDIM + c0 + gc;
    }

    __shared__ float pre[2][BT][3 * CT];   // 3 KB preactivation exchange

    unsigned* myc = cnt + bg * 32;         // 128B-spaced per-b-group counter

    for (int t = 0; t < T_STEPS; ++t) {
        // write out h_{t-1}; safe: all x[.,t-1,.] reads finished before last barrier
        if (tid < 128 && t > 0)
            out[out_base + (size_t)(t - 1) * NDIM] = hprev;

        float4v acc = {0.f, 0.f, 0.f, 0.f};
        if (g == 0) {
            const unsigned short* xr = xpk + ((size_t)(b0 + m) * T_STEPS + t) * 1024;
#pragma unroll
            for (int ch = 0; ch < 16; ++ch) {
                short8 ah = {0,0,0,0,0,0,0,0}, al = {0,0,0,0,0,0,0,0};
                if (m < BT) {
                    ah = *(const short8*)(xr + ch * 32 + q * 8);
                    al = *(const short8*)(xr + 512 + ch * 32 + q * 8);
                }
                acc = __builtin_amdgcn_mfma_f32_16x16x32_bf16(ah, wh[ch], acc, 0, 0, 0);
                acc = __builtin_amdgcn_mfma_f32_16x16x32_bf16(ah, wl[ch], acc, 0, 0, 0);
                acc = __builtin_amdgcn_mfma_f32_16x16x32_bf16(al, wh[ch], acc, 0, 0, 0);
            }
        } else if (t > 0) {
            const unsigned short* hr = hbuf + ((size_t)((t & 1) * BATCH + (b0 + m))) * NDIM;
#pragma unroll
            for (int ch = 0; ch < 16; ++ch) {
                short8 ah = {0,0,0,0,0,0,0,0}, al = {0,0,0,0,0,0,0,0};
                if (m < BT) {
                    ah = *(const short8*)(hr + ch * 32 + q * 8);
                    al = *(const short8*)(hr + 65536 + ch * 32 + q * 8);  // lo plane
                }
                acc = __builtin_amdgcn_mfma_f32_16x16x32_bf16(ah, wh[ch], acc, 0, 0, 0);
                acc = __builtin_amdgcn_mfma_f32_16x16x32_bf16(ah, wl[ch], acc, 0, 0, 0);
                acc = __builtin_amdgcn_mfma_f32_16x16x32_bf16(al, wh[ch], acc, 0, 0, 0);
            }
        }
        // C/D layout: col = lane&15 (gate col), row = q*4 + i (b-row)
#pragma unroll
        for (int i = 0; i < 4; ++i) {
            int r = q * 4 + i;
            if (r < BT) pre[g][r][nt * 16 + m] = acc[i];
        }
        __syncthreads();

        if (tid < 128) {
            float xr_ = pre[0][gb][gc]      + bxr;
            float xz_ = pre[0][gb][16 + gc] + bxz;
            float xn_ = pre[0][gb][32 + gc] + bxn;
            float hr_ = pre[1][gb][gc]      + bhr;
            float hz_ = pre[1][gb][16 + gc] + bhz;
            float hn_ = pre[1][gb][32 + gc] + bhn;
            float rg = 1.f / (1.f + __expf(-(xr_ + hr_)));
            float zg = 1.f / (1.f + __expf(-(xz_ + hz_)));
            float ng = tanhf(xn_ + rg * hn_);
            float hnew = (1.f - zg) * ng + zg * hprev;
            hprev = hnew;
            unsigned short hh = f2bf(hnew);
            unsigned short hl = f2bf(hnew - bf2f(hh));
            size_t widx = (size_t)(((t + 1) & 1) * BATCH + (b0 + gb)) * NDIM + c0 + gc;
            hbuf[widx]         = hh;
            hbuf[65536 + widx] = hl;
        }
        __syncthreads();  // drains vmcnt -> all WG stores are in L2 before fence

        // per-b-group barrier: monotonic counter, never reset (32 arrivals/step)
        if (tid == 0) {
            __threadfence();  // agent release: wbL2 (flush h/out to LLC)
            __hip_atomic_fetch_add(myc, 1u, __ATOMIC_RELEASE, __HIP_MEMORY_SCOPE_AGENT);
            const unsigned tgt = (unsigned)(t + 1) * CGRP;
            while (__hip_atomic_load(myc, __ATOMIC_ACQUIRE, __HIP_MEMORY_SCOPE_AGENT) < tgt)
                __builtin_amdgcn_s_sleep(1);
            __threadfence();  // agent acquire: inv L1/L2 (weights live in VGPRs)
        }
        __syncthreads();
    }

    if (tid < 128)
        out[out_base + (size_t)(T_STEPS - 1) * NDIM] = hprev;
}

extern "C" void kernel_launch(void* const* d_in, const int* in_sizes, int n_in,
                              void* d_out, int out_size, void* d_ws, size_t ws_size,
                              hipStream_t stream) {
    const float* h_enc = (const float*)d_in[0];
    const float* Wih   = (const float*)d_in[1];
    const float* Whh   = (const float*)d_in[2];
    const float* bih   = (const float*)d_in[3];
    const float* bhh   = (const float*)d_in[4];
    float* out = (float*)d_out;

    // ws layout: hi plane [2][64][512] u16 (128KB) + lo plane (128KB) + counters
    unsigned short* hbuf = (unsigned short*)d_ws;
    unsigned* cnt = (unsigned*)((char*)d_ws + (size_t)2 * 2 * BATCH * NDIM * sizeof(unsigned short));
    hipMemsetAsync(cnt, 0, 4096, stream);  // ws is poisoned 0xAA each launch

    // Phase 1: 64*1000*512 elems / 4 per thread / 256 per block = 32000 blocks
    hipLaunchKernelGGL(pack_split, dim3(32000), dim3(256), 0, stream,
                       h_enc, (unsigned short*)d_out);

    // Phase 2: cooperative persistent scan
    const unsigned short* xpk = (const unsigned short*)d_out;
    void* args[] = { (void*)&xpk, (void*)&out, (void*)&Wih, (void*)&Whh,
                     (void*)&bih, (void*)&bhh, (void*)&hbuf, (void*)&cnt };
    hipLaunchCooperativeKernel((const void*)gru_scan, dim3(NBLK), dim3(NTHR),
                               args, 0, stream);
    (void)in_sizes; (void)n_in; (void)out_size; (void)ws_size;
}

// Round 3
// 7456.886 us; speedup vs baseline: 2.5942x; 2.5942x over previous
//
#include <hip/hip_runtime.h>

// GRU decoder: B=64, T=1000, N=512.  R3: R2 + race fix.
// - out aliases the packed-x buffer. out[b,t-1] may only be written once ALL
//   WGs in the b-group finished step t-1 (their X reads of x[.,t-1]). That is
//   exactly what the inter-WG counter (cnt >= t*CGRP) certifies, and every
//   wave learns it at barrier b1. So the out write moved AFTER b1 (R2 had it
//   at the top of the step -> race, replay-validation failure).
// - out writes now sc0 sc1 (LLC-direct): no cross-XCD dirty-line merge needed.
// - Everything else identical to R2 (fence-free LLC-coherent h exchange,
//   relaxed agent atomic counter, LDS h-staging, VGPR-resident split weights).

#define T_STEPS 1000
#define NDIM    512
#define BATCH   64
#define BT      8
#define CT      16
#define CGRP    32     // WGs per b-group
#define BGRP    8
#define NBLK    256
#define NTHR    384

using short8  = __attribute__((ext_vector_type(8))) short;
using float4v = __attribute__((ext_vector_type(4))) float;
using uint4v  = __attribute__((ext_vector_type(4))) unsigned int;

__device__ __forceinline__ unsigned short f2bf(float f) {
    unsigned u = __float_as_uint(f);
    return (unsigned short)((u + 0x7FFFu + ((u >> 16) & 1u)) >> 16);  // RNE
}
__device__ __forceinline__ float bf2f(unsigned short h) {
    return __uint_as_float(((unsigned)h) << 16);
}

// ---- LLC-coherent (system-scope) accesses: bypass L1/L2, no fences needed ----
__device__ __forceinline__ void llc_store_u16(void* p, unsigned v) {
    asm volatile("global_store_short %0, %1, off sc0 sc1" :: "v"(p), "v"(v) : "memory");
}
__device__ __forceinline__ void llc_store_f32(void* p, float v) {
    asm volatile("global_store_dword %0, %1, off sc0 sc1" :: "v"(p), "v"(v) : "memory");
}
__device__ __forceinline__ uint4v llc_load_b128(const void* p) {
    uint4v d;
    asm volatile("global_load_dwordx4 %0, %1, off sc0 sc1" : "=v"(d) : "v"(p) : "memory");
    return d;
}
__device__ __forceinline__ void vm_drain() {
    asm volatile("s_waitcnt vmcnt(0)" ::: "memory");
}

// ---------- Phase 1: split h_enc into bf16 hi/lo planes packed in d_out ----------
__global__ void pack_split(const float* __restrict__ x, unsigned short* __restrict__ out) {
    size_t i = ((size_t)blockIdx.x * blockDim.x + threadIdx.x) * 4;
    size_t row = i >> 9;
    int    k   = (int)(i & 511);
    const float4 v = *(const float4*)(x + i);
    float vv[4] = {v.x, v.y, v.z, v.w};
    unsigned short h0 = f2bf(vv[0]), h1 = f2bf(vv[1]), h2 = f2bf(vv[2]), h3 = f2bf(vv[3]);
    ushort4 hi = {h0, h1, h2, h3};
    ushort4 lo = {f2bf(vv[0] - bf2f(h0)), f2bf(vv[1] - bf2f(h1)),
                  f2bf(vv[2] - bf2f(h2)), f2bf(vv[3] - bf2f(h3))};
    unsigned short* r = out + row * 1024;
    *(ushort4*)(r + k)       = hi;
    *(ushort4*)(r + 512 + k) = lo;
}

// ---------- Phase 2: persistent scan ----------
__global__ void __launch_bounds__(NTHR, 2) gru_scan(
    const unsigned short* xpk,   // aliases out
    float* out,
    const float* __restrict__ Wih, const float* __restrict__ Whh,
    const float* __restrict__ bih, const float* __restrict__ bhh,
    unsigned short* hbuf,        // ws: hi plane [2][64][512] u16, then lo plane
    unsigned* cnt)
{
    const int tid  = threadIdx.x;
    const int wave = tid >> 6;
    const int lane = tid & 63;
    const int m    = lane & 15;
    const int q    = lane >> 4;
    const int wg   = blockIdx.x;
    const int bg   = wg & (BGRP - 1);
    const int cg   = wg >> 3;
    const int b0   = bg * BT;
    const int c0   = cg * CT;
    const int g    = (wave >= 3) ? 1 : 0;
    const int nt   = wave - 3 * g;

    // ---- persistent weight fragments ----
    const float* W    = g ? Whh : Wih;
    const float* wrow = W + (size_t)((nt << 9) + c0 + m) * NDIM;
    short8 wh[16], wl[16];
#pragma unroll
    for (int ch = 0; ch < 16; ++ch) {
        const float* p = wrow + ch * 32 + q * 8;
        short8 h8, l8;
#pragma unroll
        for (int j = 0; j < 8; ++j) {
            float w = p[j];
            unsigned short hb = f2bf(w);
            h8[j] = (short)hb;
            l8[j] = (short)f2bf(w - bf2f(hb));
        }
        wh[ch] = h8; wl[ch] = l8;
    }

    // ---- gating-thread state (threads 0..127 in waves 0,1) ----
    const int gb = tid >> 4;
    const int gc = tid & 15;
    float bxr = 0, bxz = 0, bxn = 0, bhr = 0, bhz = 0, bhn = 0, hprev = 0.f;
    size_t out_base = 0;
    if (tid < 128) {
        int cglob = c0 + gc;
        bxr = bih[cglob]; bxz = bih[512 + cglob]; bxn = bih[1024 + cglob];
        bhr = bhh[cglob]; bhz = bhh[512 + cglob]; bhn = bhh[1024 + cglob];
        out_base = ((size_t)(b0 + gb) * T_STEPS) * NDIM + c0 + gc;
    }

    __shared__ float pre[2][BT][3 * CT];          // 3 KB
    __shared__ unsigned short hstage[8192];       // 16 KB: [plane][k16][m][8]
    __shared__ int hflag;

    unsigned* myc = cnt + bg * 32;
    if (tid == 0) hflag = 0;
    __syncthreads();

    for (int t = 0; t < T_STEPS; ++t) {
        if (wave < 3) {
            // ---- X path: cached loads from xpk ----
            float4v a0 = {0.f,0.f,0.f,0.f}, a1 = {0.f,0.f,0.f,0.f};
            const unsigned short* xr = xpk + ((size_t)(b0 + m) * T_STEPS + t) * 1024;
#pragma unroll
            for (int ch = 0; ch < 16; ++ch) {
                short8 ah = {0,0,0,0,0,0,0,0}, al = {0,0,0,0,0,0,0,0};
                if (m < BT) {
                    ah = *(const short8*)(xr + ch * 32 + q * 8);
                    al = *(const short8*)(xr + 512 + ch * 32 + q * 8);
                }
                if (ch & 1) {
                    a1 = __builtin_amdgcn_mfma_f32_16x16x32_bf16(ah, wh[ch], a1, 0, 0, 0);
                    a1 = __builtin_amdgcn_mfma_f32_16x16x32_bf16(ah, wl[ch], a1, 0, 0, 0);
                    a1 = __builtin_amdgcn_mfma_f32_16x16x32_bf16(al, wh[ch], a1, 0, 0, 0);
                } else {
                    a0 = __builtin_amdgcn_mfma_f32_16x16x32_bf16(ah, wh[ch], a0, 0, 0, 0);
                    a0 = __builtin_amdgcn_mfma_f32_16x16x32_bf16(ah, wl[ch], a0, 0, 0, 0);
                    a0 = __builtin_amdgcn_mfma_f32_16x16x32_bf16(al, wh[ch], a0, 0, 0, 0);
                }
            }
#pragma unroll
            for (int i = 0; i < 4; ++i) {
                int r = q * 4 + i;
                if (r < BT) pre[0][r][nt * 16 + m] = a0[i] + a1[i];
            }
        } else if (t > 0) {
            // ---- barrier wait (wave-3 lane0 polls LLC counter, broadcasts via LDS) ----
            if (tid == 192) {
                const unsigned tgt = (unsigned)t * CGRP;
                while (__hip_atomic_load(myc, __ATOMIC_RELAXED, __HIP_MEMORY_SCOPE_AGENT) < tgt) {}
                __hip_atomic_store(&hflag, t, __ATOMIC_RELEASE, __HIP_MEMORY_SCOPE_WORKGROUP);
            }
            while (__hip_atomic_load(&hflag, __ATOMIC_ACQUIRE, __HIP_MEMORY_SCOPE_WORKGROUP) < t) {}
            // ---- stage h slot (t&1) into LDS: 1024 x 16B chunks over 192 threads ----
            const int slot = t & 1;
            const int cb = tid - 192;
            uint4v d0, d1, d2, d3, d4, d5;
            const unsigned short* hb_s = hbuf + (size_t)(slot * 64 + b0) * 512;
#pragma unroll
            for (int k = 0; k < 5; ++k) {
                int c = cb + k * 192;
                int plane = c >> 9, rem = c & 511, r = rem >> 6, k16 = rem & 63;
                const unsigned short* gp = hb_s + plane * 65536 + (size_t)r * 512 + k16 * 8;
                uint4v v = llc_load_b128(gp);
                if (k == 0) d0 = v; else if (k == 1) d1 = v; else if (k == 2) d2 = v;
                else if (k == 3) d3 = v; else d4 = v;
            }
            if (cb < 64) {
                int c = cb + 960;
                int plane = c >> 9, rem = c & 511, r = rem >> 6, k16 = rem & 63;
                d5 = llc_load_b128(hb_s + plane * 65536 + (size_t)r * 512 + k16 * 8);
            }
            vm_drain();
#pragma unroll
            for (int k = 0; k < 5; ++k) {
                int c = cb + k * 192;
                int plane = c >> 9, rem = c & 511, r = rem >> 6, k16 = rem & 63;
                unsigned u = plane * 512 + k16 * 8 + r;
                uint4v v = (k == 0) ? d0 : (k == 1) ? d1 : (k == 2) ? d2 : (k == 3) ? d3 : d4;
                *(uint4v*)&hstage[u * 8] = v;
            }
            if (cb < 64) {
                int c = cb + 960;
                int plane = c >> 9, rem = c & 511, r = rem >> 6, k16 = rem & 63;
                *(uint4v*)&hstage[(plane * 512 + k16 * 8 + r) * 8] = d5;
            }
        }
        __syncthreads();   // b1: hstage + pre[0] ready; cnt >= t*CGRP certified

        // Safe ONLY here: all WGs in b-group finished step t-1 => all X reads of
        // x[., t-1] are done => overwriting that row (out aliases xpk) is race-free.
        if (tid < 128 && t > 0)
            llc_store_f32(&out[out_base + (size_t)(t - 1) * NDIM], hprev);

        if (wave >= 3) {
            float4v a0 = {0.f,0.f,0.f,0.f}, a1 = {0.f,0.f,0.f,0.f};
            if (t > 0) {
#pragma unroll
                for (int ch = 0; ch < 16; ++ch) {
                    short8 ah = {0,0,0,0,0,0,0,0}, al = {0,0,0,0,0,0,0,0};
                    if (m < BT) {
                        int u = (ch * 4 + q) * 8 + m;
                        ah = *(const short8*)&hstage[u * 8];
                        al = *(const short8*)&hstage[4096 + u * 8];
                    }
                    if (ch & 1) {
                        a1 = __builtin_amdgcn_mfma_f32_16x16x32_bf16(ah, wh[ch], a1, 0, 0, 0);
                        a1 = __builtin_amdgcn_mfma_f32_16x16x32_bf16(ah, wl[ch], a1, 0, 0, 0);
                        a1 = __builtin_amdgcn_mfma_f32_16x16x32_bf16(al, wh[ch], a1, 0, 0, 0);
                    } else {
                        a0 = __builtin_amdgcn_mfma_f32_16x16x32_bf16(ah, wh[ch], a0, 0, 0, 0);
                        a0 = __builtin_amdgcn_mfma_f32_16x16x32_bf16(ah, wl[ch], a0, 0, 0, 0);
                        a0 = __builtin_amdgcn_mfma_f32_16x16x32_bf16(al, wh[ch], a0, 0, 0, 0);
                    }
                }
            }
#pragma unroll
            for (int i = 0; i < 4; ++i) {
                int r = q * 4 + i;
                if (r < BT) pre[1][r][nt * 16 + m] = a0[i] + a1[i];
            }
        }
        __syncthreads();   // b2: pre[1] ready

        if (tid < 128) {
            float xr_ = pre[0][gb][gc]      + bxr;
            float xz_ = pre[0][gb][16 + gc] + bxz;
            float xn_ = pre[0][gb][32 + gc] + bxn;
            float hr_ = pre[1][gb][gc]      + bhr;
            float hz_ = pre[1][gb][16 + gc] + bhz;
            float hn_ = pre[1][gb][32 + gc] + bhn;
            float rg = 1.f / (1.f + __expf(-(xr_ + hr_)));
            float zg = 1.f / (1.f + __expf(-(xz_ + hz_)));
            float ng = tanhf(xn_ + rg * hn_);
            float hnew = (1.f - zg) * ng + zg * hprev;
            hprev = hnew;
            unsigned short hh = f2bf(hnew);
            unsigned short hl = f2bf(hnew - bf2f(hh));
            size_t widx = (size_t)(((t + 1) & 1) * BATCH + (b0 + gb)) * NDIM + c0 + gc;
            llc_store_u16(hbuf + widx,         (unsigned)hh);
            llc_store_u16(hbuf + 65536 + widx, (unsigned)hl);
            vm_drain();    // h stores (and the out store) acked at coherence point
        }
        __syncthreads();   // b3: all gating stores globally visible

        if (tid == 0)
            __hip_atomic_fetch_add(myc, 1u, __ATOMIC_RELAXED, __HIP_MEMORY_SCOPE_AGENT);
    }

    if (tid < 128)
        llc_store_f32(&out[out_base + (size_t)(T_STEPS - 1) * NDIM], hprev);
}

extern "C" void kernel_launch(void* const* d_in, const int* in_sizes, int n_in,
                              void* d_out, int out_size, void* d_ws, size_t ws_size,
                              hipStream_t stream) {
    const float* h_enc = (const float*)d_in[0];
    const float* Wih   = (const float*)d_in[1];
    const float* Whh   = (const float*)d_in[2];
    const float* bih   = (const float*)d_in[3];
    const float* bhh   = (const float*)d_in[4];
    float* out = (float*)d_out;

    unsigned short* hbuf = (unsigned short*)d_ws;
    unsigned* cnt = (unsigned*)((char*)d_ws + (size_t)2 * 2 * BATCH * NDIM * sizeof(unsigned short));
    hipMemsetAsync(cnt, 0, 4096, stream);

    hipLaunchKernelGGL(pack_split, dim3(32000), dim3(256), 0, stream,
                       h_enc, (unsigned short*)d_out);

    const unsigned short* xpk = (const unsigned short*)d_out;
    void* args[] = { (void*)&xpk, (void*)&out, (void*)&Wih, (void*)&Whh,
                     (void*)&bih, (void*)&bhh, (void*)&hbuf, (void*)&cnt };
    hipLaunchCooperativeKernel((const void*)gru_scan, dim3(NBLK), dim3(NTHR),
                               args, 0, stream);
    (void)in_sizes; (void)n_in; (void)out_size; (void)ws_size;
}